// Round 8
// baseline (3934.888 us; speedup 1.0000x reference)
//
#include <hip/hip_runtime.h>
#include <hip/hip_bf16.h>
#include <math.h>

#define DD   43      // hidden size
#define TT   2048
#define BB   256
#define FEAT 8
#define MB   16      // batches per block (MFMA M)
#define NPAD 192     // 4 gates x 48 padded rows
#define ROWS 88      // out row stride (shorts): [fwd 0..42 | pad 43 | bwd 44..86 | pad 87]
#define NH1  30
#define NH2  20

using bf16 = __hip_bfloat16;
typedef __attribute__((ext_vector_type(8))) short bf16x8;   // MFMA A frag
typedef __attribute__((ext_vector_type(4))) int   i32x4;    // MFMA B frag (AGPR)
typedef __attribute__((ext_vector_type(4))) float f32x4;    // MFMA C/D frag
typedef __attribute__((ext_vector_type(2))) unsigned u32x2; // 8B chunk

__device__ __forceinline__ float ldv(const float* p) { return *p; }
__device__ __forceinline__ float ldv(const bf16* p)  { return __bfloat162float(*p); }

__device__ __forceinline__ short f2b(float f) {
    bf16 h = __float2bfloat16(f);
    return *reinterpret_cast<short*>(&h);
}
#define LOG2E 1.44269504f
__device__ __forceinline__ float sig_(float x) {
    return __builtin_amdgcn_rcpf(1.0f + __builtin_amdgcn_exp2f(-LOG2E * x));
}
__device__ __forceinline__ float tanh_(float x) {
    return fmaf(-2.0f, __builtin_amdgcn_rcpf(1.0f + __builtin_amdgcn_exp2f(2.0f * LOG2E * x)), 1.0f);
}
__device__ __forceinline__ bf16x8 mk8(const unsigned u[4]) {
    union { unsigned u[4]; bf16x8 v; } x;
    x.u[0] = u[0]; x.u[1] = u[1]; x.u[2] = u[2]; x.u[3] = u[3];
    return x.v;
}
// MFMA with B operand pinned to AGPR class.
__device__ __forceinline__ void mfma_a(f32x4& d, bf16x8 a, i32x4 b) {
    asm("v_mfma_f32_16x16x32_bf16 %0, %1, %2, %0" : "+v"(d) : "v"(a), "a"(b));
}

// ---------------- prep: gate-padded bf16 weight blocks + combined fp32 biases ----
// Row n in [0,192): gate q = n/48, dq = n%48, original row = q*43+dq (dq<43, else 0).
// W1 [2][192][96] : k<8 = w_ih1 @ w_proj (proj folded), k in [32,75) = w_hh1, else 0.
// W2 [2][192][160]: k<43 = w_ih2[:,k]; k in [44,87) = w_ih2[:,k-1] (seam pad at 43);
//                   k in [96,139) = w_hh2; else 0.   (matches ROWS=88 x-layout)
__global__ void prep_kernel(
    const float* __restrict__ wp, const float* __restrict__ bp,
    const float* __restrict__ w_ih1f, const float* __restrict__ w_hh1f,
    const float* __restrict__ b_ih1f, const float* __restrict__ b_hh1f,
    const float* __restrict__ w_ih1b, const float* __restrict__ w_hh1b,
    const float* __restrict__ b_ih1b, const float* __restrict__ b_hh1b,
    const float* __restrict__ w_ih2f, const float* __restrict__ w_hh2f,
    const float* __restrict__ b_ih2f, const float* __restrict__ b_hh2f,
    const float* __restrict__ w_ih2b, const float* __restrict__ w_hh2b,
    const float* __restrict__ b_ih2b, const float* __restrict__ b_hh2b,
    short* __restrict__ W1, short* __restrict__ W2,
    float* __restrict__ bias1, float* __restrict__ bias2)
{
    const int KP1 = 96, KP2 = 160;
    const int S1 = 2 * NPAD * KP1, S2 = 2 * NPAD * KP2, S3 = 2 * NPAD;
    int idx = blockIdx.x * blockDim.x + threadIdx.x;
    if (idx < S1) {
        int dir = idx / (NPAD * KP1), rem = idx % (NPAD * KP1);
        int n = rem / KP1, k = rem % KP1;
        int q = n / 48, dq = n % 48;
        float v = 0.0f;
        if (dq < DD) {
            int orig = q * DD + dq;
            const float* wih = dir ? w_ih1b : w_ih1f;
            const float* whh = dir ? w_hh1b : w_hh1f;
            if (k < FEAT) {
                for (int d = 0; d < DD; ++d) v = fmaf(wih[orig * DD + d], wp[d * FEAT + k], v);
            } else if (k >= 32 && k < 32 + DD) {
                v = whh[orig * DD + (k - 32)];
            }
        }
        W1[idx] = f2b(v);
    } else if (idx < S1 + S2) {
        int j = idx - S1;
        int dir = j / (NPAD * KP2), rem = j % (NPAD * KP2);
        int n = rem / KP2, k = rem % KP2;
        int q = n / 48, dq = n % 48;
        float v = 0.0f;
        if (dq < DD) {
            int orig = q * DD + dq;
            const float* wih = dir ? w_ih2b : w_ih2f;
            const float* whh = dir ? w_hh2b : w_hh2f;
            if (k < DD)                        v = wih[orig * (2 * DD) + k];
            else if (k >= 44 && k < 44 + DD)   v = wih[orig * (2 * DD) + (k - 1)];
            else if (k >= 96 && k < 96 + DD)   v = whh[orig * DD + (k - 96)];
        }
        W2[j] = f2b(v);
    } else if (idx < S1 + S2 + S3) {
        int j = idx - S1 - S2;
        int dir = j / NPAD, n = j % NPAD;
        int q = n / 48, dq = n % 48;
        float v = 0.0f;
        if (dq < DD) {
            int orig = q * DD + dq;
            const float* wih = dir ? w_ih1b : w_ih1f;
            const float* bi  = dir ? b_ih1b : b_ih1f;
            const float* bh  = dir ? b_hh1b : b_hh1f;
            v = bi[orig] + bh[orig];
            for (int d = 0; d < DD; ++d) v = fmaf(wih[orig * DD + d], bp[d], v);
        }
        bias1[j] = v;
    } else if (idx < S1 + S2 + 2 * S3) {
        int j = idx - S1 - S2 - S3;
        int dir = j / NPAD, n = j % NPAD;
        int q = n / 48, dq = n % 48;
        float v = 0.0f;
        if (dq < DD) {
            int orig = q * DD + dq;
            const float* bi = dir ? b_ih2b : b_ih2f;
            const float* bh = dir ? b_hh2b : b_hh2f;
            v = bi[orig] + bh[orig];
        }
        bias2[j] = v;
    }
}

// ---------------- MFMA BiLSTM layer, gate-aligned, 3 waves, 1 barrier/step ----
// Per-step h stays in LDS (hbuf + out-tile); global stores happen only once per
// 8 steps as coalesced 8B-chunk bursts (keeps the vmcnt queue clean so x-load
// waits are never blocked behind scattered-store retirement).
template <int KSX, bool XRAW>
__global__ __launch_bounds__(192, 1)
void lstm_mfma(
    const void*  __restrict__ in_,     // XRAW ? fp32 [B][T][8] : bf16 [B][T][ROWS]
    const short* __restrict__ Wb,      // [2][NPAD][KPAD] bf16 bits
    const float* __restrict__ bias,    // [2][NPAD]
    short* __restrict__ out)           // [B][T][ROWS]; this block fills dir's 44-short half
{
    constexpr int KS   = KSX + 2;      // x K-steps + 2 for h (43 -> 64 pad)
    constexpr int KPAD = KS * 32;

    const int dir   = blockIdx.x & 1;
    const int btile = blockIdx.x >> 1;
    const int tid   = threadIdx.x;
    const int lane  = tid & 63;
    const int wv    = tid >> 6;        // 0..2
    const int ln15  = lane & 15;
    const int lg    = lane >> 4;       // 0..3

    __shared__ __align__(16) short hbuf[2][MB][72];    // bf16 h (dbuf), cols 43..63 = 0
    __shared__ __align__(16) short tile[2][8][MB][44]; // out-staging, dbuf per 8-step group

    const int  dq   = wv * 16 + ln15;  // 0..47, valid < 43
    const bool dval = dq < DD;

    // ---- weights -> AGPRs (loaded once) ----
    i32x4 wx[4][KSX];
    i32x4 wh[4][2];
    float bv[4];
    {
        const short* Wd = Wb + (size_t)dir * NPAD * KPAD;
#pragma unroll
        for (int q = 0; q < 4; ++q) {
            const short* row = Wd + (size_t)(q * 48 + dq) * KPAD;
#pragma unroll
            for (int ks = 0; ks < KSX; ++ks)
                wx[q][ks] = *reinterpret_cast<const i32x4*>(row + ks * 32 + lg * 8);
            wh[q][0] = *reinterpret_cast<const i32x4*>(row + KSX * 32 + lg * 8);
            wh[q][1] = *reinterpret_cast<const i32x4*>(row + (KSX + 1) * 32 + lg * 8);
            bv[q] = bias[dir * NPAD + q * 48 + dq];
        }
#pragma unroll
        for (int q = 0; q < 4; ++q) {
#pragma unroll
            for (int ks = 0; ks < KSX; ++ks)
                asm volatile("" : "+a"(wx[q][ks]));
            asm volatile("" : "+a"(wh[q][0]), "+a"(wh[q][1]));
        }
    }

    for (int i = tid; i < 2 * MB * 72; i += 192) ((short*)hbuf)[i] = 0;

    const long t0  = dir ? (TT - 1) : 0;
    const int  stp = dir ? -1 : 1;
    const int  bb  = btile * MB + ln15;          // batch this lane feeds into A-frags
    const int  bt0 = btile * MB;

    unsigned xe[KSX][4], xo[KSX][4];
    auto load_x = [&](long t, unsigned (&xf)[KSX][4]) {
        long tc = t < 0 ? 0 : (t >= TT ? TT - 1 : t);
        if constexpr (XRAW) {
            if (lg == 0) {
                const float* xp = (const float*)in_ + ((size_t)bb * TT + tc) * FEAT;
                float4 v0 = *reinterpret_cast<const float4*>(xp);
                float4 v1 = *reinterpret_cast<const float4*>(xp + 4);
                xf[0][0] = ((unsigned)(unsigned short)f2b(v0.y) << 16) | (unsigned short)f2b(v0.x);
                xf[0][1] = ((unsigned)(unsigned short)f2b(v0.w) << 16) | (unsigned short)f2b(v0.z);
                xf[0][2] = ((unsigned)(unsigned short)f2b(v1.y) << 16) | (unsigned short)f2b(v1.x);
                xf[0][3] = ((unsigned)(unsigned short)f2b(v1.w) << 16) | (unsigned short)f2b(v1.z);
            } else {
#pragma unroll
                for (int j = 0; j < 4; ++j) xf[0][j] = 0u;
            }
        } else {
            const short* xp = (const short*)in_ + ((size_t)bb * TT + tc) * ROWS;
#pragma unroll
            for (int ks = 0; ks < KSX; ++ks) {
                int k0 = ks * 32 + lg * 8;
#pragma unroll
                for (int j = 0; j < 4; ++j) {
                    unsigned v = 0u;
                    if (k0 < ROWS) v = *reinterpret_cast<const unsigned*>(xp + k0 + 2 * j);
                    xf[ks][j] = v;
                }
            }
        }
    };

    // xacc = bias + W_x . x(t)  (off the h-critical path)
    auto xinit = [&](unsigned (&xf)[KSX][4], f32x4 (&xa)[4]) {
#pragma unroll
        for (int q = 0; q < 4; ++q) {
            f32x4 a = {bv[q], bv[q], bv[q], bv[q]};
#pragma unroll
            for (int ks = 0; ks < KSX; ++ks)
                mfma_a(a, mk8(xf[ks]), wx[q][ks]);
            xa[q] = a;
        }
    };

    float cc[4] = {0.0f, 0.0f, 0.0f, 0.0f};
    f32x4 xaccE[4], xaccO[4];

    load_x(t0, xe);
    load_x(t0 + stp, xo);
    __syncthreads();            // hbuf zeros visible (full drain OK once)
    xinit(xe, xaccE);

    auto step = [&](unsigned (&cur)[KSX][4], unsigned (&oth)[KSX][4],
                    f32x4 (&accC)[4], f32x4 (&accN)[4], int par, int s, long t) {
        bf16x8 ah0 = *reinterpret_cast<const bf16x8*>(&hbuf[par][ln15][lg * 8]);
        bf16x8 ah1 = *reinterpret_cast<const bf16x8*>(&hbuf[par][ln15][32 + lg * 8]);
#pragma unroll
        for (int q = 0; q < 4; ++q) {
            mfma_a(accC[q], ah0, wh[q][0]);
            mfma_a(accC[q], ah1, wh[q][1]);
        }
        load_x(t + 2 * stp, cur);     // prefetch 2 steps ahead (floats across barrier)
        xinit(oth, accN);             // next step's x-part (MFMA pipe, overlaps acts)

        const int ti = (int)(t & 7);
        short* tw = &tile[(s >> 3) & 1][ti][lg * 4][0];
#pragma unroll
        for (int r = 0; r < 4; ++r) {
            float ig = sig_(accC[0][r]);
            float fg = sig_(accC[1][r]);
            float gg = tanh_(accC[2][r]);
            float og = sig_(accC[3][r]);
            cc[r] = fmaf(fg, cc[r], ig * gg);
            float h = og * tanh_(cc[r]);
            short hb = f2b(h);
            if (dval) hbuf[par ^ 1][lg * 4 + r][dq] = hb;   // pad cols stay 0
            if (dq < 44) tw[r * 44 + dq] = hb;              // out staging (pad d=43 finite)
        }
        // barrier waits LDS only -- vmem loads stay in flight
        asm volatile("s_waitcnt lgkmcnt(0)" ::: "memory");
        __builtin_amdgcn_sched_barrier(0);
        __builtin_amdgcn_s_barrier();

        // flush: once per 8 steps, tile -> global as coalesced 8B chunks
        if ((s & 7) == 7) {
            const short* tp = &tile[(s >> 3) & 1][0][0][0];
            long tbase = t & ~7L;
#pragma unroll
            for (int i = 0; i < 8; ++i) {
                int c = i * 192 + tid;            // 128 rows x 11 chunks = 1408
                if (c < 128 * 11) {
                    int row = c / 11, sub = c - row * 11;
                    int tr = row >> 4, b = row & 15;
                    u32x2 v = *reinterpret_cast<const u32x2*>(tp + row * 44 + sub * 4);
                    *reinterpret_cast<u32x2*>(
                        out + ((size_t)(bt0 + b) * TT + (tbase + tr)) * ROWS
                            + dir * 44 + sub * 4) = v;
                }
            }
        }
    };

    long t = t0;
    for (int s = 0; s < TT; s += 2) {
        step(xe, xo, xaccE, xaccO, 0, s, t);     t += stp;
        step(xo, xe, xaccO, xaccE, 1, s + 1, t); t += stp;
    }
}

// ---------------- dense head: per (b,t): 86 -> 30 -> 20 -> 1 ----------------
__global__ void head_kernel(const short* __restrict__ h2,   // [BT][ROWS] bf16 bits
                            const float* __restrict__ w1, const float* __restrict__ b1,
                            const float* __restrict__ w2, const float* __restrict__ b2,
                            const float* __restrict__ w3, const float* __restrict__ b3,
                            float* __restrict__ outp) {
    long bt = (long)blockIdx.x * blockDim.x + threadIdx.x;
    if (bt >= (long)BB * TT) return;
    const bf16* src = (const bf16*)(h2 + (size_t)bt * ROWS);
    float v[2 * DD];
#pragma unroll
    for (int k = 0; k < 2 * DD; ++k) {
        int kp = (k < DD) ? k : k + 1;         // seam pad at phys 43
        v[k] = ldv(&src[kp]);
    }
    float m1[NH1];
#pragma unroll
    for (int j = 0; j < NH1; ++j) {
        float a = b1[j];
        const float* w = w1 + j * (2 * DD);
#pragma unroll
        for (int k = 0; k < 2 * DD; ++k) a = fmaf(w[k], v[k], a);
        m1[j] = fmaxf(a, 0.0f);
    }
    float m2[NH2];
#pragma unroll
    for (int j = 0; j < NH2; ++j) {
        float a = b2[j];
        const float* w = w2 + j * NH1;
#pragma unroll
        for (int k = 0; k < NH1; ++k) a = fmaf(w[k], m1[k], a);
        m2[j] = fmaxf(a, 0.0f);
    }
    float a = b3[0];
#pragma unroll
    for (int k = 0; k < NH2; ++k) a = fmaf(w3[k], m2[k], a);
    outp[bt] = a;
}

extern "C" void kernel_launch(void* const* d_in, const int* in_sizes, int n_in,
                              void* d_out, int out_size, void* d_ws, size_t ws_size,
                              hipStream_t stream) {
    const float* x      = (const float*)d_in[0];
    const float* w_proj = (const float*)d_in[1];
    const float* b_proj = (const float*)d_in[2];
    const float* w_ih1f = (const float*)d_in[3];
    const float* w_hh1f = (const float*)d_in[4];
    const float* b_ih1f = (const float*)d_in[5];
    const float* b_hh1f = (const float*)d_in[6];
    const float* w_ih1b = (const float*)d_in[7];
    const float* w_hh1b = (const float*)d_in[8];
    const float* b_ih1b = (const float*)d_in[9];
    const float* b_hh1b = (const float*)d_in[10];
    const float* w_ih2f = (const float*)d_in[11];
    const float* w_hh2f = (const float*)d_in[12];
    const float* b_ih2f = (const float*)d_in[13];
    const float* b_hh2f = (const float*)d_in[14];
    const float* w_ih2b = (const float*)d_in[15];
    const float* w_hh2b = (const float*)d_in[16];
    const float* b_ih2b = (const float*)d_in[17];
    const float* b_hh2b = (const float*)d_in[18];
    const float* w_d1   = (const float*)d_in[19];
    const float* b_d1   = (const float*)d_in[20];
    const float* w_d2   = (const float*)d_in[21];
    const float* b_d2   = (const float*)d_in[22];
    const float* w_out  = (const float*)d_in[23];
    const float* b_out  = (const float*)d_in[24];
    (void)in_sizes; (void)n_in; (void)out_size; (void)ws_size;

    // workspace: [W1 | W2 | bias1 | bias2 | pad->256KB | out1 | out2] (out rows = 88 shorts)
    char* wsb = (char*)d_ws;
    short* W1    = (short*)(wsb);                         // 2*192*96*2  = 73728 B
    short* W2    = (short*)(wsb + 73728);                 // 2*192*160*2 = 122880 B
    float* bias1 = (float*)(wsb + 73728 + 122880);        // 1536 B
    float* bias2 = (float*)(wsb + 73728 + 122880 + 1536);
    const size_t o_big  = 262144;
    const size_t lay_sz = (size_t)BB * TT * ROWS * sizeof(short);   // 92.3 MB
    short* out1 = (short*)(wsb + o_big);
    short* out2 = (short*)(wsb + o_big + lay_sz);

    {
        const int total = 2 * NPAD * 96 + 2 * NPAD * 160 + 2 * (2 * NPAD);
        prep_kernel<<<(total + 255) / 256, 256, 0, stream>>>(
            w_proj, b_proj,
            w_ih1f, w_hh1f, b_ih1f, b_hh1f, w_ih1b, w_hh1b, b_ih1b, b_hh1b,
            w_ih2f, w_hh2f, b_ih2f, b_hh2f, w_ih2b, w_hh2b, b_ih2b, b_hh2b,
            W1, W2, bias1, bias2);
    }
    // layer 1: raw fp32 x (proj folded), KSX=1
    lstm_mfma<1, true><<<2 * (BB / MB), 192, 0, stream>>>(x, W1, bias1, out1);
    // layer 2: bf16 out1 rows, KSX=3
    lstm_mfma<3, false><<<2 * (BB / MB), 192, 0, stream>>>(out1, W2, bias2, out2);
    // head
    head_kernel<<<(int)(((long)BB * TT + 255) / 256), 256, 0, stream>>>(
        out2, w_d1, b_d1, w_d2, b_d2, w_out, b_out, (float*)d_out);
}